// Round 1
// baseline (617.157 us; speedup 1.0000x reference)
//
#include <hip/hip_runtime.h>
#include <cstdint>
#include <cstddef>

#define NN 20000   // nodes
#define NE 320000  // edges
#define D  128     // embed dim
#define TW 8       // towers
#define FT 16      // per-tower features
#define NL 3       // layers
#define NS 4096    // subgraphs
#define INR 512    // (NL+1)*D

// ---------------- CSR build ----------------

__global__ void count_kernel(const int* __restrict__ ei, const int* __restrict__ sub,
                             int* __restrict__ deg, int* __restrict__ scnt) {
    int i = blockIdx.x * blockDim.x + threadIdx.x;
    if (i < NE) atomicAdd(&deg[ei[NE + i]], 1);   // dst row
    if (i < NN) atomicAdd(&scnt[sub[i]], 1);
}

// single-block exclusive scan (n up to ~20480)
__global__ void scan_kernel(const int* __restrict__ cnt, int* __restrict__ off, int n) {
    __shared__ int lds[1024];
    const int tid = threadIdx.x;
    const int per = (n + 1023) >> 10;
    const int s = tid * per;
    const int e = min(s + per, n);
    int sum = 0;
    for (int i = s; i < e; ++i) sum += cnt[i];
    lds[tid] = sum;
    __syncthreads();
    for (int o = 1; o < 1024; o <<= 1) {
        int v = (tid >= o) ? lds[tid - o] : 0;
        __syncthreads();
        if (tid >= o) lds[tid] += v;
        __syncthreads();
    }
    int base = (tid == 0) ? 0 : lds[tid - 1];
    for (int i = s; i < e; ++i) { off[i] = base; base += cnt[i]; }
    if (tid == 1023) off[n] = lds[1023];
}

__global__ void fill_kernel(const int* __restrict__ ei, const int* __restrict__ sub,
                            const int* __restrict__ eoff, int* __restrict__ ecur,
                            int* __restrict__ csr,
                            const int* __restrict__ soff, int* __restrict__ scur,
                            int* __restrict__ snodes) {
    int i = blockIdx.x * blockDim.x + threadIdx.x;
    if (i < NE) {
        int dd = ei[NE + i];
        int p = atomicAdd(&ecur[dd], 1);
        csr[eoff[dd] + p] = ei[i];          // src
    }
    if (i < NN) {
        int g = sub[i];
        int p = atomicAdd(&scur[g], 1);
        snodes[soff[g] + p] = i;
    }
}

// ---------------- layer pipeline ----------------

__global__ void copyx_kernel(const float* __restrict__ x, float* __restrict__ xc) {
    int i = blockIdx.x * blockDim.x + threadIdx.x;
    if (i >= NN * D) return;
    int n = i >> 7, d = i & (D - 1);
    xc[(size_t)n * INR + d] = x[i];
}

// s_buf[n,:] = sum over in-edges of xc[src, l*D : l*D+D]
__global__ __launch_bounds__(256)
void gather_kernel(const float* __restrict__ xc, const int* __restrict__ eoff,
                   const int* __restrict__ csr, float* __restrict__ sbuf, int l) {
    const int node = blockIdx.x * 2 + (threadIdx.x >> 7);
    const int d = threadIdx.x & (D - 1);
    if (node >= NN) return;
    const int e0 = eoff[node], e1 = eoff[node + 1];
    const float* base = xc + (size_t)l * D + d;
    float acc = 0.f;
    for (int e = e0; e < e1; ++e) {
        int s = csr[e];
        acc += base[(size_t)s * INR];
    }
    sbuf[(size_t)node * D + d] = acc;
}

// per-node PNA update: agg -> post -> lin -> relu, writes next xc column block
__global__ __launch_bounds__(512)
void update_kernel(float* __restrict__ xc, const float* __restrict__ sbuf,
                   const int* __restrict__ deg,
                   const float* __restrict__ pre_w, const float* __restrict__ pre_b,
                   const float* __restrict__ post_w, const float* __restrict__ post_b,
                   const float* __restrict__ lin_w, const float* __restrict__ lin_b,
                   int l) {
    __shared__ float lds_lin[D * D];     // 64 KB
    __shared__ float lds_xt[4][D];
    __shared__ float lds_sv[4][D];
    __shared__ float lds_agg[4][D];
    __shared__ float lds_o[4][D];

    const int tid = threadIdx.x;
    const int si  = tid >> 7;            // sub-node slot 0..3
    const int d   = tid & (D - 1);
    const int t16 = d & ~15;             // tower base t*16

    // per-thread tower weights: thread (t,g)=d only needs row d (64 floats)
    float wpa[FT], wpb[FT], wqa[FT], wqb[FT];
    const float* pw = pre_w  + (size_t)l * (TW * FT * 2 * FT) + (size_t)d * (2 * FT);
    const float* qw = post_w + (size_t)l * (TW * FT * 2 * FT) + (size_t)d * (2 * FT);
#pragma unroll
    for (int f = 0; f < FT; ++f) {
        wpa[f] = pw[f];      wpb[f] = pw[FT + f];
        wqa[f] = qw[f];      wqb[f] = qw[FT + f];
    }
    const float bpre  = pre_b [l * D + d];
    const float bpost = post_b[l * D + d];
    const float blin  = lin_b [l * D + d];

    const float* lw = lin_w + (size_t)l * D * D;
    for (int i = tid; i < D * D; i += 512) lds_lin[i] = lw[i];
    __syncthreads();

    for (int n0 = blockIdx.x * 4; n0 < NN; n0 += gridDim.x * 4) {
        const int node = n0 + si;
        const bool act = node < NN;
        float xt_d = 0.f, sv_d = 0.f, degf = 0.f;
        if (act) {
            xt_d = xc[(size_t)node * INR + (size_t)l * D + d];
            sv_d = sbuf[(size_t)node * D + d];
            degf = (float)deg[node];
        }
        lds_xt[si][d] = xt_d;
        lds_sv[si][d] = sv_d;
        __syncthreads();

        // agg = deg*(A x + pre_b) + B s
        float a = bpre, b = 0.f;
        const float* xl = &lds_xt[si][t16];
        const float* sl = &lds_sv[si][t16];
#pragma unroll
        for (int f = 0; f < FT; ++f) {
            a = fmaf(wpa[f], xl[f], a);
            b = fmaf(wpb[f], sl[f], b);
        }
        lds_agg[si][d] = fmaf(degf, a, b);
        __syncthreads();

        // o = postA x + postB agg + post_b
        float o = bpost;
        const float* al = &lds_agg[si][t16];
#pragma unroll
        for (int f = 0; f < FT; ++f) {
            o = fmaf(wqa[f], xl[f], o);
            o = fmaf(wqb[f], al[f], o);
        }
        lds_o[si][d] = o;
        __syncthreads();

        // h = relu(lin_w @ o + lin_b); rotation k=(k0+d)&127 keeps LDS conflict-free
        float h = blin;
        const float* ol = lds_o[si];
        const float* lrow = &lds_lin[(size_t)d * D];
#pragma unroll 16
        for (int k0 = 0; k0 < D; ++k0) {
            int k = (k0 + d) & (D - 1);
            h = fmaf(lrow[k], ol[k], h);
        }
        if (act) xc[(size_t)node * INR + (size_t)(l + 1) * D + d] = fmaxf(h, 0.f);
        __syncthreads();
    }
}

// ---------------- pooling + fused BN/out ----------------

__global__ __launch_bounds__(512)
void pool_kernel(const float* __restrict__ xc, const int* __restrict__ soff,
                 const int* __restrict__ snodes, float* __restrict__ pooled) {
    const int s = blockIdx.x;
    const int j = threadIdx.x;
    const int a0 = soff[s], a1 = soff[s + 1];
    float acc = 0.f;
    for (int a = a0; a < a1; ++a) {
        int n = snodes[a];
        acc += xc[(size_t)n * INR + j];
    }
    pooled[(size_t)s * INR + j] = acc;
}

__global__ void weff_kernel(const float* __restrict__ op_w, const float* __restrict__ gma,
                            const float* __restrict__ var, float* __restrict__ wefft) {
    int i = blockIdx.x * blockDim.x + threadIdx.x;
    if (i >= INR * D) return;
    int j = i >> 7, d = i & (D - 1);
    float sc = gma[j] * rsqrtf(var[j] + 1e-5f);
    wefft[(size_t)j * D + d] = op_w[(size_t)d * INR + j] * sc;
}

__global__ void beff_kernel(const float* __restrict__ op_w, const float* __restrict__ op_b,
                            const float* __restrict__ gma, const float* __restrict__ bta,
                            const float* __restrict__ mean, const float* __restrict__ var,
                            float* __restrict__ beff) {
    int d = threadIdx.x;  // 128
    float acc = op_b[d];
    for (int j = 0; j < INR; ++j) {
        float sc = gma[j] * rsqrtf(var[j] + 1e-5f);
        float sh = bta[j] - mean[j] * sc;
        acc = fmaf(op_w[(size_t)d * INR + j], sh, acc);
    }
    beff[d] = acc;
}

__global__ __launch_bounds__(128)
void out_kernel(const float* __restrict__ pooled, const float* __restrict__ wefft,
                const float* __restrict__ beff, float* __restrict__ out) {
    __shared__ float pl[16 * INR];   // 32 KB
    const int d = threadIdx.x;
    const int s0 = blockIdx.x * 16;
    for (int i = d; i < 16 * INR; i += 128) pl[i] = pooled[(size_t)s0 * INR + i];
    __syncthreads();
    float acc[16];
#pragma unroll
    for (int i = 0; i < 16; ++i) acc[i] = 0.f;
    for (int j = 0; j < INR; ++j) {
        float w = wefft[(size_t)j * D + d];   // coalesced
#pragma unroll
        for (int i = 0; i < 16; ++i) acc[i] = fmaf(pl[i * INR + j], w, acc[i]);  // LDS broadcast
    }
    const float bb = beff[d];
#pragma unroll
    for (int i = 0; i < 16; ++i) out[(size_t)(s0 + i) * D + d] = acc[i] + bb;
}

// ---------------- launch ----------------

extern "C" void kernel_launch(void* const* d_in, const int* in_sizes, int n_in,
                              void* d_out, int out_size, void* d_ws, size_t ws_size,
                              hipStream_t stream) {
    const float* x      = (const float*)d_in[0];
    const int*   ei     = (const int*)d_in[1];
    const int*   sub    = (const int*)d_in[2];
    const float* pre_w  = (const float*)d_in[3];
    const float* pre_b  = (const float*)d_in[4];
    const float* post_w = (const float*)d_in[5];
    const float* post_b = (const float*)d_in[6];
    const float* lin_w  = (const float*)d_in[7];
    const float* lin_b  = (const float*)d_in[8];
    const float* bn_g   = (const float*)d_in[9];
    const float* bn_b   = (const float*)d_in[10];
    const float* bn_m   = (const float*)d_in[11];
    const float* bn_v   = (const float*)d_in[12];
    const float* op_w   = (const float*)d_in[13];
    const float* op_b   = (const float*)d_in[14];
    float* out = (float*)d_out;

    char* p = (char*)d_ws;
    auto alloc = [&](size_t bytes) -> char* {
        char* q = p;
        p += (bytes + 255) & ~(size_t)255;
        return q;
    };

    // zeroed group (contiguous)
    char* zero_start = p;
    int* deg  = (int*)alloc(sizeof(int) * NN);
    int* ecur = (int*)alloc(sizeof(int) * NN);
    int* scnt = (int*)alloc(sizeof(int) * NS);
    int* scur = (int*)alloc(sizeof(int) * NS);
    size_t zero_span = (size_t)(p - zero_start);
    // rest
    int* eoff   = (int*)alloc(sizeof(int) * (NN + 1));
    int* soff   = (int*)alloc(sizeof(int) * (NS + 1));
    int* csr    = (int*)alloc(sizeof(int) * NE);
    int* snodes = (int*)alloc(sizeof(int) * NN);
    float* xc     = (float*)alloc(sizeof(float) * (size_t)NN * INR);
    float* sbuf   = (float*)alloc(sizeof(float) * (size_t)NN * D);
    float* pooled = (float*)alloc(sizeof(float) * (size_t)NS * INR);
    float* wefft  = (float*)alloc(sizeof(float) * (size_t)INR * D);
    float* beff   = (float*)alloc(sizeof(float) * D);

    hipMemsetAsync(zero_start, 0, zero_span, stream);

    count_kernel<<<(NE + 255) / 256, 256, 0, stream>>>(ei, sub, deg, scnt);
    scan_kernel<<<1, 1024, 0, stream>>>(deg, eoff, NN);
    scan_kernel<<<1, 1024, 0, stream>>>(scnt, soff, NS);
    fill_kernel<<<(NE + 255) / 256, 256, 0, stream>>>(ei, sub, eoff, ecur, csr,
                                                      soff, scur, snodes);
    copyx_kernel<<<(NN * D + 255) / 256, 256, 0, stream>>>(x, xc);

    for (int l = 0; l < NL; ++l) {
        gather_kernel<<<NN / 2, 256, 0, stream>>>(xc, eoff, csr, sbuf, l);
        update_kernel<<<512, 512, 0, stream>>>(xc, sbuf, deg, pre_w, pre_b,
                                               post_w, post_b, lin_w, lin_b, l);
    }

    weff_kernel<<<(INR * D + 255) / 256, 256, 0, stream>>>(op_w, bn_g, bn_v, wefft);
    beff_kernel<<<1, 128, 0, stream>>>(op_w, op_b, bn_g, bn_b, bn_m, bn_v, beff);
    pool_kernel<<<NS, 512, 0, stream>>>(xc, soff, snodes, pooled);
    out_kernel<<<NS / 16, 128, 0, stream>>>(pooled, wefft, beff, out);
}

// Round 3
// 390.436 us; speedup vs baseline: 1.5807x; 1.5807x over previous
//
#include <hip/hip_runtime.h>
#include <cstdint>
#include <cstddef>

#define NN 20000   // nodes
#define NE 320000  // edges
#define D  128     // embed dim
#define TW 8       // towers
#define FT 16      // per-tower features
#define NL 3       // layers
#define NS 4096    // subgraphs
#define INR 512    // (NL+1)*D

// ---------------- CSR build ----------------

__global__ void count_kernel(const int* __restrict__ ei, const int* __restrict__ sub,
                             int* __restrict__ deg, int* __restrict__ scnt) {
    int i = blockIdx.x * blockDim.x + threadIdx.x;
    if (i < NE) atomicAdd(&deg[ei[NE + i]], 1);   // dst row
    if (i < NN) atomicAdd(&scnt[sub[i]], 1);
}

// two-block scan: block 0 -> (deg->eoff, NN), block 1 -> (scnt->soff, NS)
__global__ void scan2_kernel(const int* __restrict__ cnt0, int* __restrict__ off0,
                             const int* __restrict__ cnt1, int* __restrict__ off1) {
    __shared__ int lds[1024];
    const int tid = threadIdx.x;
    const int* cnt = blockIdx.x ? cnt1 : cnt0;
    int*       off = blockIdx.x ? off1 : off0;
    const int n   = blockIdx.x ? NS : NN;
    const int per = (n + 1023) >> 10;
    const int s = tid * per;
    const int e = min(s + per, n);
    int sum = 0;
    for (int i = s; i < e; ++i) sum += cnt[i];
    lds[tid] = sum;
    __syncthreads();
    for (int o = 1; o < 1024; o <<= 1) {
        int v = (tid >= o) ? lds[tid - o] : 0;
        __syncthreads();
        if (tid >= o) lds[tid] += v;
        __syncthreads();
    }
    int base = (tid == 0) ? 0 : lds[tid - 1];
    for (int i = s; i < e; ++i) { off[i] = base; base += cnt[i]; }
    if (tid == 1023) off[n] = lds[1023];
}

__global__ void fill_kernel(const int* __restrict__ ei, const int* __restrict__ sub,
                            const int* __restrict__ eoff, int* __restrict__ ecur,
                            int* __restrict__ csr,
                            const int* __restrict__ soff, int* __restrict__ scur,
                            int* __restrict__ snodes) {
    int i = blockIdx.x * blockDim.x + threadIdx.x;
    if (i < NE) {
        int dd = ei[NE + i];
        int p = atomicAdd(&ecur[dd], 1);
        csr[eoff[dd] + p] = ei[i];          // src
    }
    if (i < NN) {
        int g = sub[i];
        int p = atomicAdd(&scur[g], 1);
        snodes[soff[g] + p] = i;
    }
}

// ---------------- per-layer tower-weight folding ----------------
// o = post_b + postA.x + (postB.B).s + deg*((postB.A).x + postB.pre_b)
// cw[lt][dd][0:16]=M1=postA row, [16:32]=M2=postB.A row, [32:48]=M3=postB.B row; cv=postB.pre_b
__global__ void towerprep_kernel(const float* __restrict__ pre_w, const float* __restrict__ pre_b,
                                 const float* __restrict__ post_w,
                                 float* __restrict__ cw, float* __restrict__ cv) {
    const int lt = blockIdx.x;                 // l*TW + t, 24 blocks
    const int dd = threadIdx.x >> 4;
    const int ff = threadIdx.x & 15;
    const float* PW = pre_w  + (size_t)lt * (FT * 2 * FT);
    const float* QW = post_w + (size_t)lt * (FT * 2 * FT);
    const float* PB = pre_b  + (size_t)lt * FT;
    float m1 = QW[dd * 32 + ff];
    float m2 = 0.f, m3 = 0.f, v = 0.f;
    for (int k = 0; k < FT; ++k) {
        float pb = QW[dd * 32 + 16 + k];
        m2 = fmaf(pb, PW[k * 32 + ff], m2);
        m3 = fmaf(pb, PW[k * 32 + 16 + ff], m3);
        if (ff == 0) v = fmaf(pb, PB[k], v);
    }
    float* o = cw + ((size_t)lt * 16 + dd) * 48;
    o[ff] = m1; o[16 + ff] = m2; o[32 + ff] = m3;
    if (ff == 0) cv[lt * 16 + dd] = v;
}

// ---------------- gather: sbuf[n,:] = sum_{src in in(n)} h[src,:] ----------------
__global__ __launch_bounds__(256)
void gather_kernel(const float* __restrict__ h, const int* __restrict__ eoff,
                   const int* __restrict__ csr, float* __restrict__ sbuf) {
    const int wid  = threadIdx.x >> 6;
    const int lane = threadIdx.x & 63;
    const int node = blockIdx.x * 4 + wid;
    if (node >= NN) return;
    const int e0 = eoff[node], e1 = eoff[node + 1];
    const float2* h2 = (const float2*)h;
    float ax = 0.f, ay = 0.f;
    int e = e0;
    for (; e + 4 <= e1; e += 4) {
        int s0 = csr[e], s1 = csr[e + 1], s2 = csr[e + 2], s3 = csr[e + 3];
        float2 a = h2[(size_t)s0 * 64 + lane];
        float2 b = h2[(size_t)s1 * 64 + lane];
        float2 c = h2[(size_t)s2 * 64 + lane];
        float2 d = h2[(size_t)s3 * 64 + lane];
        ax += a.x + b.x + c.x + d.x;
        ay += a.y + b.y + c.y + d.y;
    }
    for (; e < e1; ++e) {
        int s = csr[e];
        float2 a = h2[(size_t)s * 64 + lane];
        ax += a.x; ay += a.y;
    }
    float2 r; r.x = ax; r.y = ay;
    ((float2*)sbuf)[(size_t)node * 64 + lane] = r;
}

// ---------------- fused PNA update ----------------
__global__ __launch_bounds__(512, 4)
void update_kernel(const float* __restrict__ hin, const float* __restrict__ sbuf,
                   const int* __restrict__ deg,
                   const float* __restrict__ cw, const float* __restrict__ cv,
                   const float* __restrict__ post_b, const float* __restrict__ lin_w,
                   const float* __restrict__ lin_b, float* __restrict__ hout, int l) {
    __shared__ float LW[D * 132];     // 67584 B, padded rows (stride 132 -> conflict-free b128)
    __shared__ float OB[16 * D];      // 8192 B
    __shared__ float XA[4 * D];       // 2048 B
    __shared__ float SB[4 * D];       // 2048 B

    const int tid = threadIdx.x;
    const int si  = tid >> 7;          // 0..3
    const int d   = tid & 127;
    const int t16 = d & ~15;
    const int dd  = d & 15;

    // combined tower weights: row d needs 48 floats
    const float* wb = cw + ((size_t)(l * TW + (d >> 4)) * 16 + dd) * 48;
    float4 M1[4], M2[4], M3[4];
#pragma unroll
    for (int q = 0; q < 4; ++q) {
        M1[q] = ((const float4*)wb)[q];
        M2[q] = ((const float4*)(wb + 16))[q];
        M3[q] = ((const float4*)(wb + 32))[q];
    }
    const float vq = cv[(l * TW + (d >> 4)) * 16 + dd];
    const float cb = post_b[l * D + d];
    const float bl = lin_b[l * D + d];

    const float* lw = lin_w + (size_t)l * D * D;
    for (int i = tid; i < D * D; i += 512) LW[(i >> 7) * 132 + (i & 127)] = lw[i];

    const int ntiles = (NN + 15) >> 4;
    for (int tile = blockIdx.x; tile < ntiles; tile += gridDim.x) {
        const int n0 = tile << 4;
#pragma unroll
        for (int p = 0; p < 4; ++p) {
            __syncthreads();                       // protects XA/SB reuse (and lin staging, 1st iter)
            const int node = n0 + p * 4 + si;
            float xv = 0.f, sv = 0.f, dg = 0.f;
            if (node < NN) {
                xv = hin[(size_t)node * D + d];
                sv = sbuf[(size_t)node * D + d];
                dg = (float)deg[node];
            }
            XA[si * 128 + d] = xv;
            SB[si * 128 + d] = sv;
            __syncthreads();
            float ax = 0.f, am = 0.f, as = 0.f;
            const float4* xa = (const float4*)&XA[si * 128 + t16];
            const float4* sb = (const float4*)&SB[si * 128 + t16];
#pragma unroll
            for (int q = 0; q < 4; ++q) {
                float4 xq = xa[q], sq = sb[q];
                ax = fmaf(M1[q].x, xq.x, ax); ax = fmaf(M1[q].y, xq.y, ax);
                ax = fmaf(M1[q].z, xq.z, ax); ax = fmaf(M1[q].w, xq.w, ax);
                am = fmaf(M2[q].x, xq.x, am); am = fmaf(M2[q].y, xq.y, am);
                am = fmaf(M2[q].z, xq.z, am); am = fmaf(M2[q].w, xq.w, am);
                as = fmaf(M3[q].x, sq.x, as); as = fmaf(M3[q].y, sq.y, as);
                as = fmaf(M3[q].z, sq.z, as); as = fmaf(M3[q].w, sq.w, as);
            }
            OB[(p * 4 + si) * 128 + d] = cb + ax + as + dg * (am + vq);
        }
        __syncthreads();
        // matvec: group si handles nodes n0+si*4 .. +3, thread computes output row d
        float ac0 = 0.f, ac1 = 0.f, ac2 = 0.f, ac3 = 0.f;
        const float4* lrow = (const float4*)&LW[d * 132];
        const float4* ob   = (const float4*)&OB[si * 4 * 128];
#pragma unroll 8
        for (int k0 = 0; k0 < 32; ++k0) {
            float4 lv = lrow[k0];
            float4 o0 = ob[k0];
            float4 o1 = ob[32 + k0];
            float4 o2 = ob[64 + k0];
            float4 o3 = ob[96 + k0];
            ac0 = fmaf(lv.x, o0.x, ac0); ac0 = fmaf(lv.y, o0.y, ac0);
            ac0 = fmaf(lv.z, o0.z, ac0); ac0 = fmaf(lv.w, o0.w, ac0);
            ac1 = fmaf(lv.x, o1.x, ac1); ac1 = fmaf(lv.y, o1.y, ac1);
            ac1 = fmaf(lv.z, o1.z, ac1); ac1 = fmaf(lv.w, o1.w, ac1);
            ac2 = fmaf(lv.x, o2.x, ac2); ac2 = fmaf(lv.y, o2.y, ac2);
            ac2 = fmaf(lv.z, o2.z, ac2); ac2 = fmaf(lv.w, o2.w, ac2);
            ac3 = fmaf(lv.x, o3.x, ac3); ac3 = fmaf(lv.y, o3.y, ac3);
            ac3 = fmaf(lv.z, o3.z, ac3); ac3 = fmaf(lv.w, o3.w, ac3);
        }
        const int nb = n0 + si * 4;
        if (nb + 0 < NN) hout[(size_t)(nb + 0) * D + d] = fmaxf(ac0 + bl, 0.f);
        if (nb + 1 < NN) hout[(size_t)(nb + 1) * D + d] = fmaxf(ac1 + bl, 0.f);
        if (nb + 2 < NN) hout[(size_t)(nb + 2) * D + d] = fmaxf(ac2 + bl, 0.f);
        if (nb + 3 < NN) hout[(size_t)(nb + 3) * D + d] = fmaxf(ac3 + bl, 0.f);
        __syncthreads();                           // OB reuse next tile
    }
}

// ---------------- pooling + fused BN/out ----------------

__global__ __launch_bounds__(128)
void pool_kernel(const float* __restrict__ h0, const float* __restrict__ h1,
                 const float* __restrict__ h2, const float* __restrict__ h3,
                 const int* __restrict__ soff, const int* __restrict__ snodes,
                 float* __restrict__ pooled) {
    const int s = blockIdx.x;
    const int t = threadIdx.x;
    const int seg = t >> 5, q = t & 31;
    const float* hs = (seg == 0) ? h0 : (seg == 1) ? h1 : (seg == 2) ? h2 : h3;
    const int a0 = soff[s], a1 = soff[s + 1];
    float4 acc = make_float4(0.f, 0.f, 0.f, 0.f);
    for (int a = a0; a < a1; ++a) {
        int n = snodes[a];
        float4 v = ((const float4*)hs)[(size_t)n * 32 + q];
        acc.x += v.x; acc.y += v.y; acc.z += v.z; acc.w += v.w;
    }
    ((float4*)pooled)[(size_t)s * 128 + seg * 32 + q] = acc;
}

__global__ void weff_kernel(const float* __restrict__ op_w, const float* __restrict__ gma,
                            const float* __restrict__ var, float* __restrict__ wefft) {
    int i = blockIdx.x * blockDim.x + threadIdx.x;
    if (i >= INR * D) return;
    int j = i >> 7, d = i & (D - 1);
    float sc = gma[j] * rsqrtf(var[j] + 1e-5f);
    wefft[(size_t)j * D + d] = op_w[(size_t)d * INR + j] * sc;
}

__global__ __launch_bounds__(64)
void beff_kernel(const float* __restrict__ op_w, const float* __restrict__ op_b,
                 const float* __restrict__ gma, const float* __restrict__ bta,
                 const float* __restrict__ mean, const float* __restrict__ var,
                 float* __restrict__ beff) {
    const int d = blockIdx.x;      // 128 blocks
    const int lane = threadIdx.x;  // 64
    float acc = 0.f;
    for (int j = lane; j < INR; j += 64) {
        float sc = gma[j] * rsqrtf(var[j] + 1e-5f);
        float sh = bta[j] - mean[j] * sc;
        acc = fmaf(op_w[(size_t)d * INR + j], sh, acc);
    }
#pragma unroll
    for (int o = 32; o; o >>= 1) acc += __shfl_down(acc, o);
    if (lane == 0) beff[d] = acc + op_b[d];
}

// 16 subgraphs/block, 512 threads = 4 j-quarters x 128 d
__global__ __launch_bounds__(512)
void out_kernel(const float* __restrict__ pooled, const float* __restrict__ wefft,
                const float* __restrict__ beff, float* __restrict__ out) {
    __shared__ float sm[16 * INR];   // 32 KB; phase2 reuses as partial[4][16][128]
    const int tid = threadIdx.x;
    const int q = tid >> 7;
    const int d = tid & 127;
    const int s0 = blockIdx.x * 16;
    {
        const float4* src = (const float4*)(pooled + (size_t)s0 * INR);
        float4* dst = (float4*)sm;
        for (int i = tid; i < 16 * INR / 4; i += 512) dst[i] = src[i];
    }
    __syncthreads();
    float acc[16];
#pragma unroll
    for (int i = 0; i < 16; ++i) acc[i] = 0.f;
    for (int jj = 0; jj < 128; ++jj) {
        int j = q * 128 + jj;
        float w = wefft[(size_t)j * D + d];
#pragma unroll
        for (int i = 0; i < 16; ++i) acc[i] = fmaf(sm[i * INR + j], w, acc[i]);
    }
    __syncthreads();
#pragma unroll
    for (int i = 0; i < 16; ++i) sm[(q * 16 + i) * 128 + d] = acc[i];
    __syncthreads();
    const float bb = beff[d];
#pragma unroll
    for (int ii = 0; ii < 4; ++ii) {
        int i = q * 4 + ii;
        float v = sm[i * 128 + d] + sm[(16 + i) * 128 + d]
                + sm[(32 + i) * 128 + d] + sm[(48 + i) * 128 + d];
        out[(size_t)(s0 + i) * D + d] = v + bb;
    }
}

// ---------------- launch ----------------

extern "C" void kernel_launch(void* const* d_in, const int* in_sizes, int n_in,
                              void* d_out, int out_size, void* d_ws, size_t ws_size,
                              hipStream_t stream) {
    const float* x      = (const float*)d_in[0];
    const int*   ei     = (const int*)d_in[1];
    const int*   sub    = (const int*)d_in[2];
    const float* pre_w  = (const float*)d_in[3];
    const float* pre_b  = (const float*)d_in[4];
    const float* post_w = (const float*)d_in[5];
    const float* post_b = (const float*)d_in[6];
    const float* lin_w  = (const float*)d_in[7];
    const float* lin_b  = (const float*)d_in[8];
    const float* bn_g   = (const float*)d_in[9];
    const float* bn_b   = (const float*)d_in[10];
    const float* bn_m   = (const float*)d_in[11];
    const float* bn_v   = (const float*)d_in[12];
    const float* op_w   = (const float*)d_in[13];
    const float* op_b   = (const float*)d_in[14];
    float* out = (float*)d_out;

    char* p = (char*)d_ws;
    auto alloc = [&](size_t bytes) -> char* {
        char* q = p;
        p += (bytes + 255) & ~(size_t)255;
        return q;
    };

    char* zero_start = p;
    int* deg  = (int*)alloc(sizeof(int) * NN);
    int* ecur = (int*)alloc(sizeof(int) * NN);
    int* scnt = (int*)alloc(sizeof(int) * NS);
    int* scur = (int*)alloc(sizeof(int) * NS);
    size_t zero_span = (size_t)(p - zero_start);

    int* eoff   = (int*)alloc(sizeof(int) * (NN + 1));
    int* soff   = (int*)alloc(sizeof(int) * (NS + 1));
    int* csr    = (int*)alloc(sizeof(int) * NE);
    int* snodes = (int*)alloc(sizeof(int) * NN);
    float* h1     = (float*)alloc(sizeof(float) * (size_t)NN * D);
    float* h2     = (float*)alloc(sizeof(float) * (size_t)NN * D);
    float* h3     = (float*)alloc(sizeof(float) * (size_t)NN * D);
    float* sbuf   = (float*)alloc(sizeof(float) * (size_t)NN * D);
    float* pooled = (float*)alloc(sizeof(float) * (size_t)NS * INR);
    float* wefft  = (float*)alloc(sizeof(float) * (size_t)INR * D);
    float* beff   = (float*)alloc(sizeof(float) * D);
    float* cw     = (float*)alloc(sizeof(float) * NL * TW * 16 * 48);
    float* cv     = (float*)alloc(sizeof(float) * NL * TW * 16);

    hipMemsetAsync(zero_start, 0, zero_span, stream);

    count_kernel<<<(NE + 255) / 256, 256, 0, stream>>>(ei, sub, deg, scnt);
    scan2_kernel<<<2, 1024, 0, stream>>>(deg, eoff, scnt, soff);
    fill_kernel<<<(NE + 255) / 256, 256, 0, stream>>>(ei, sub, eoff, ecur, csr,
                                                      soff, scur, snodes);
    towerprep_kernel<<<NL * TW, 256, 0, stream>>>(pre_w, pre_b, post_w, cw, cv);
    weff_kernel<<<(INR * D) / 256, 256, 0, stream>>>(op_w, bn_g, bn_v, wefft);
    beff_kernel<<<D, 64, 0, stream>>>(op_w, op_b, bn_g, bn_b, bn_m, bn_v, beff);

    const float* hs[4] = { x, h1, h2, h3 };
    for (int l = 0; l < NL; ++l) {
        gather_kernel<<<(NN + 3) / 4, 256, 0, stream>>>(hs[l], eoff, csr, sbuf);
        update_kernel<<<640, 512, 0, stream>>>(hs[l], sbuf, deg, cw, cv,
                                               post_b, lin_w, lin_b,
                                               (float*)hs[l + 1], l);
    }

    pool_kernel<<<NS, 128, 0, stream>>>(x, h1, h2, h3, soff, snodes, pooled);
    out_kernel<<<NS / 16, 512, 0, stream>>>(pooled, wefft, beff, out);
}

// Round 5
// 355.047 us; speedup vs baseline: 1.7382x; 1.0997x over previous
//
#include <hip/hip_runtime.h>
#include <cstdint>
#include <cstddef>

#define NN 20000   // nodes
#define NE 320000  // edges
#define D  128     // embed dim
#define TW 8       // towers
#define FT 16      // per-tower features
#define NL 3       // layers
#define NS 4096    // subgraphs
#define INR 512    // (L+1)*D

// ---------------- CSR build ----------------

__global__ void count_kernel(const int* __restrict__ ei, const int* __restrict__ sub,
                             int* __restrict__ deg, int* __restrict__ scnt) {
    int i = blockIdx.x * blockDim.x + threadIdx.x;
    if (i < NE) atomicAdd(&deg[ei[NE + i]], 1);   // dst row
    if (i < NN) atomicAdd(&scnt[sub[i]], 1);
}

// two-block scan: block 0 -> (deg->eoff, NN), block 1 -> (scnt->soff, NS)
__global__ void scan2_kernel(const int* __restrict__ cnt0, int* __restrict__ off0,
                             const int* __restrict__ cnt1, int* __restrict__ off1) {
    __shared__ int lds[1024];
    const int tid = threadIdx.x;
    const int* cnt = blockIdx.x ? cnt1 : cnt0;
    int*       off = blockIdx.x ? off1 : off0;
    const int n   = blockIdx.x ? NS : NN;
    const int per = (n + 1023) >> 10;
    const int s = tid * per;
    const int e = min(s + per, n);
    int sum = 0;
    for (int i = s; i < e; ++i) sum += cnt[i];
    lds[tid] = sum;
    __syncthreads();
    for (int o = 1; o < 1024; o <<= 1) {
        int v = (tid >= o) ? lds[tid - o] : 0;
        __syncthreads();
        if (tid >= o) lds[tid] += v;
        __syncthreads();
    }
    int base = (tid == 0) ? 0 : lds[tid - 1];
    for (int i = s; i < e; ++i) { off[i] = base; base += cnt[i]; }
    if (tid == 1023) off[n] = lds[1023];
}

__global__ void fill_kernel(const int* __restrict__ ei, const int* __restrict__ sub,
                            const int* __restrict__ eoff, int* __restrict__ ecur,
                            int* __restrict__ csr,
                            const int* __restrict__ soff, int* __restrict__ scur,
                            int* __restrict__ snodes) {
    int i = blockIdx.x * blockDim.x + threadIdx.x;
    if (i < NE) {
        int dd = ei[NE + i];
        int p = atomicAdd(&ecur[dd], 1);
        csr[eoff[dd] + p] = ei[i];          // src
    }
    if (i < NN) {
        int g = sub[i];
        int p = atomicAdd(&scur[g], 1);
        snodes[soff[g] + p] = i;
    }
}

// ---------------- merged prep: towerprep (blk 0..23), weff (24..279), beff (280..311) ----
// towerprep: o = post_b + postA.x + (postB.B).s + deg*((postB.A).x + postB.pre_b)
// cw[lt][dd][0:16]=M1=postA row, [16:32]=M2=postB.A row, [32:48]=M3=postB.B row; cv=postB.pre_b
__global__ __launch_bounds__(256)
void prep_kernel(const float* __restrict__ pre_w, const float* __restrict__ pre_b,
                 const float* __restrict__ post_w,
                 float* __restrict__ cw, float* __restrict__ cv,
                 const float* __restrict__ op_w, const float* __restrict__ op_b,
                 const float* __restrict__ gma, const float* __restrict__ bta,
                 const float* __restrict__ mean, const float* __restrict__ var,
                 float* __restrict__ wefft, float* __restrict__ beff) {
    const int b = blockIdx.x;
    const int tid = threadIdx.x;
    if (b < 24) {                          // ---- tower fold
        const int lt = b;
        const int dd = tid >> 4;
        const int ff = tid & 15;
        const float* PW = pre_w  + (size_t)lt * (FT * 2 * FT);
        const float* QW = post_w + (size_t)lt * (FT * 2 * FT);
        const float* PB = pre_b  + (size_t)lt * FT;
        float m1 = QW[dd * 32 + ff];
        float m2 = 0.f, m3 = 0.f, v = 0.f;
        for (int k = 0; k < FT; ++k) {
            float pb = QW[dd * 32 + 16 + k];
            m2 = fmaf(pb, PW[k * 32 + ff], m2);
            m3 = fmaf(pb, PW[k * 32 + 16 + ff], m3);
            if (ff == 0) v = fmaf(pb, PB[k], v);
        }
        float* o = cw + ((size_t)lt * 16 + dd) * 48;
        o[ff] = m1; o[16 + ff] = m2; o[32 + ff] = m3;
        if (ff == 0) cv[lt * 16 + dd] = v;
    } else if (b < 280) {                  // ---- wefft[j][d] = op_w[d][j]*scale[j]
        int i = (b - 24) * 256 + tid;      // 65536 total
        int j = i >> 7, d = i & (D - 1);
        float sc = gma[j] * rsqrtf(var[j] + 1e-5f);
        wefft[(size_t)j * D + d] = op_w[(size_t)d * INR + j] * sc;
    } else {                               // ---- beff rows, 4 rows/block (one per wave)
        const int d = (b - 280) * 4 + (tid >> 6);
        const int lane = tid & 63;
        float acc = 0.f;
        for (int j = lane; j < INR; j += 64) {
            float sc = gma[j] * rsqrtf(var[j] + 1e-5f);
            float sh = bta[j] - mean[j] * sc;
            acc = fmaf(op_w[(size_t)d * INR + j], sh, acc);
        }
#pragma unroll
        for (int o = 32; o; o >>= 1) acc += __shfl_down(acc, o);
        if (lane == 0) beff[d] = acc + op_b[d];
    }
}

// ---------------- gather: sbuf[n,:] = sum_{src in in(n)} h[src,:] ----------------
// one wave per node; lanes 0-31 handle even edges, 32-63 odd (float4 over 128 dims)
__global__ __launch_bounds__(256)
void gather_kernel(const float* __restrict__ h, const int* __restrict__ eoff,
                   const int* __restrict__ csr, float* __restrict__ sbuf) {
    const int w    = threadIdx.x >> 6;
    const int lane = threadIdx.x & 63;
    const int node = blockIdx.x * 4 + w;
    if (node >= NN) return;
    const int e0 = eoff[node], e1 = eoff[node + 1];
    const int half = lane >> 5;
    const int q    = lane & 31;
    const float4* h4 = (const float4*)h;       // 32 float4 per node row
    float4 acc = make_float4(0.f, 0.f, 0.f, 0.f);
    int e = e0;
    for (; e + 8 <= e1; e += 8) {
#pragma unroll
        for (int k = 0; k < 4; ++k) {
            int s = csr[e + 2 * k + half];
            float4 v = h4[(size_t)s * 32 + q];
            acc.x += v.x; acc.y += v.y; acc.z += v.z; acc.w += v.w;
        }
    }
    for (; e < e1; e += 2) {
        int idx = e + half;
        bool valid = idx < e1;
        int s = csr[valid ? idx : e0];
        float4 v = h4[(size_t)s * 32 + q];
        if (valid) { acc.x += v.x; acc.y += v.y; acc.z += v.z; acc.w += v.w; }
    }
    acc.x += __shfl_xor(acc.x, 32);
    acc.y += __shfl_xor(acc.y, 32);
    acc.z += __shfl_xor(acc.z, 32);
    acc.w += __shfl_xor(acc.w, 32);
    if (half == 0) ((float4*)sbuf)[(size_t)node * 32 + q] = acc;
}

// ---------------- fused PNA update ----------------
__global__ __launch_bounds__(512, 4)
void update_kernel(const float* __restrict__ hin, const float* __restrict__ sbuf,
                   const int* __restrict__ deg,
                   const float* __restrict__ cw, const float* __restrict__ cv,
                   const float* __restrict__ post_b, const float* __restrict__ lin_w,
                   const float* __restrict__ lin_b, float* __restrict__ hout, int l) {
    __shared__ float LW[D * 132];     // 67584 B, padded rows (stride 132 -> conflict-free b128)
    __shared__ float OB[16 * D];      // 8192 B
    __shared__ float XA[4 * D];       // 2048 B
    __shared__ float SB[4 * D];       // 2048 B

    const int tid = threadIdx.x;
    const int si  = tid >> 7;          // 0..3
    const int d   = tid & 127;
    const int t16 = d & ~15;
    const int dd  = d & 15;

    const float* wb = cw + ((size_t)(l * TW + (d >> 4)) * 16 + dd) * 48;
    float4 M1[4], M2[4], M3[4];
#pragma unroll
    for (int q = 0; q < 4; ++q) {
        M1[q] = ((const float4*)wb)[q];
        M2[q] = ((const float4*)(wb + 16))[q];
        M3[q] = ((const float4*)(wb + 32))[q];
    }
    const float vq = cv[(l * TW + (d >> 4)) * 16 + dd];
    const float cb = post_b[l * D + d];
    const float bl = lin_b[l * D + d];

    const float* lw = lin_w + (size_t)l * D * D;
    for (int i = tid; i < D * D; i += 512) LW[(i >> 7) * 132 + (i & 127)] = lw[i];

    const int ntiles = (NN + 15) >> 4;
    for (int tile = blockIdx.x; tile < ntiles; tile += gridDim.x) {
        const int n0 = tile << 4;
#pragma unroll
        for (int p = 0; p < 4; ++p) {
            __syncthreads();                       // protects XA/SB reuse (and lin staging, 1st iter)
            const int node = n0 + p * 4 + si;
            float xv = 0.f, sv = 0.f, dg = 0.f;
            if (node < NN) {
                xv = hin[(size_t)node * D + d];
                sv = sbuf[(size_t)node * D + d];
                dg = (float)deg[node];
            }
            XA[si * 128 + d] = xv;
            SB[si * 128 + d] = sv;
            __syncthreads();
            float ax = 0.f, am = 0.f, as = 0.f;
            const float4* xa = (const float4*)&XA[si * 128 + t16];
            const float4* sb = (const float4*)&SB[si * 128 + t16];
#pragma unroll
            for (int q = 0; q < 4; ++q) {
                float4 xq = xa[q], sq = sb[q];
                ax = fmaf(M1[q].x, xq.x, ax); ax = fmaf(M1[q].y, xq.y, ax);
                ax = fmaf(M1[q].z, xq.z, ax); ax = fmaf(M1[q].w, xq.w, ax);
                am = fmaf(M2[q].x, xq.x, am); am = fmaf(M2[q].y, xq.y, am);
                am = fmaf(M2[q].z, xq.z, am); am = fmaf(M2[q].w, xq.w, am);
                as = fmaf(M3[q].x, sq.x, as); as = fmaf(M3[q].y, sq.y, as);
                as = fmaf(M3[q].z, sq.z, as); as = fmaf(M3[q].w, sq.w, as);
            }
            OB[(p * 4 + si) * 128 + d] = cb + ax + as + dg * (am + vq);
        }
        __syncthreads();
        // matvec: group si handles nodes n0+si*4 .. +3, thread computes output row d
        float ac0 = 0.f, ac1 = 0.f, ac2 = 0.f, ac3 = 0.f;
        const float4* lrow = (const float4*)&LW[d * 132];
        const float4* ob   = (const float4*)&OB[si * 4 * 128];
#pragma unroll 8
        for (int k0 = 0; k0 < 32; ++k0) {
            float4 lv = lrow[k0];
            float4 o0 = ob[k0];
            float4 o1 = ob[32 + k0];
            float4 o2 = ob[64 + k0];
            float4 o3 = ob[96 + k0];
            ac0 = fmaf(lv.x, o0.x, ac0); ac0 = fmaf(lv.y, o0.y, ac0);
            ac0 = fmaf(lv.z, o0.z, ac0); ac0 = fmaf(lv.w, o0.w, ac0);
            ac1 = fmaf(lv.x, o1.x, ac1); ac1 = fmaf(lv.y, o1.y, ac1);
            ac1 = fmaf(lv.z, o1.z, ac1); ac1 = fmaf(lv.w, o1.w, ac1);
            ac2 = fmaf(lv.x, o2.x, ac2); ac2 = fmaf(lv.y, o2.y, ac2);
            ac2 = fmaf(lv.z, o2.z, ac2); ac2 = fmaf(lv.w, o2.w, ac2);
            ac3 = fmaf(lv.x, o3.x, ac3); ac3 = fmaf(lv.y, o3.y, ac3);
            ac3 = fmaf(lv.z, o3.z, ac3); ac3 = fmaf(lv.w, o3.w, ac3);
        }
        const int nb = n0 + si * 4;
        if (nb + 0 < NN) hout[(size_t)(nb + 0) * D + d] = fmaxf(ac0 + bl, 0.f);
        if (nb + 1 < NN) hout[(size_t)(nb + 1) * D + d] = fmaxf(ac1 + bl, 0.f);
        if (nb + 2 < NN) hout[(size_t)(nb + 2) * D + d] = fmaxf(ac2 + bl, 0.f);
        if (nb + 3 < NN) hout[(size_t)(nb + 3) * D + d] = fmaxf(ac3 + bl, 0.f);
        __syncthreads();                           // OB reuse next tile
    }
}

// ---------------- pooling + fused BN/out ----------------

__global__ __launch_bounds__(128)
void pool_kernel(const float* __restrict__ h0, const float* __restrict__ h1,
                 const float* __restrict__ h2, const float* __restrict__ h3,
                 const int* __restrict__ soff, const int* __restrict__ snodes,
                 float* __restrict__ pooled) {
    const int s = blockIdx.x;
    const int t = threadIdx.x;
    const int seg = t >> 5, q = t & 31;
    const float* hs = (seg == 0) ? h0 : (seg == 1) ? h1 : (seg == 2) ? h2 : h3;
    const int a0 = soff[s], a1 = soff[s + 1];
    float4 acc = make_float4(0.f, 0.f, 0.f, 0.f);
    for (int a = a0; a < a1; ++a) {
        int n = snodes[a];
        float4 v = ((const float4*)hs)[(size_t)n * 32 + q];
        acc.x += v.x; acc.y += v.y; acc.z += v.z; acc.w += v.w;
    }
    ((float4*)pooled)[(size_t)s * 128 + seg * 32 + q] = acc;
}

// 16 subgraphs/block, 512 threads = 4 j-quarters x 128 d
__global__ __launch_bounds__(512)
void out_kernel(const float* __restrict__ pooled, const float* __restrict__ wefft,
                const float* __restrict__ beff, float* __restrict__ out) {
    __shared__ float sm[16 * INR];   // 32 KB; phase2 reuses as partial[4][16][128]
    const int tid = threadIdx.x;
    const int q = tid >> 7;
    const int d = tid & 127;
    const int s0 = blockIdx.x * 16;
    {
        const float4* src = (const float4*)(pooled + (size_t)s0 * INR);
        float4* dst = (float4*)sm;
        for (int i = tid; i < 16 * INR / 4; i += 512) dst[i] = src[i];
    }
    __syncthreads();
    float acc[16];
#pragma unroll
    for (int i = 0; i < 16; ++i) acc[i] = 0.f;
    // 4 jj per iteration: 4 independent global loads + 16 ds_read_b128 broadcasts + 64 FMA
    for (int jj4 = 0; jj4 < 32; ++jj4) {
        const int j0 = q * 128 + jj4 * 4;
        float wv0 = wefft[(size_t)(j0 + 0) * D + d];
        float wv1 = wefft[(size_t)(j0 + 1) * D + d];
        float wv2 = wefft[(size_t)(j0 + 2) * D + d];
        float wv3 = wefft[(size_t)(j0 + 3) * D + d];
#pragma unroll
        for (int i = 0; i < 16; ++i) {
            float4 pv = *(const float4*)&sm[i * INR + j0];
            acc[i] = fmaf(pv.x, wv0, acc[i]);
            acc[i] = fmaf(pv.y, wv1, acc[i]);
            acc[i] = fmaf(pv.z, wv2, acc[i]);
            acc[i] = fmaf(pv.w, wv3, acc[i]);
        }
    }
    __syncthreads();
#pragma unroll
    for (int i = 0; i < 16; ++i) sm[(q * 16 + i) * 128 + d] = acc[i];
    __syncthreads();
    const float bb = beff[d];
#pragma unroll
    for (int ii = 0; ii < 4; ++ii) {
        int i = q * 4 + ii;
        float v = sm[i * 128 + d] + sm[(16 + i) * 128 + d]
                + sm[(32 + i) * 128 + d] + sm[(48 + i) * 128 + d];
        out[(size_t)(s0 + i) * D + d] = v + bb;
    }
}

// ---------------- launch ----------------

extern "C" void kernel_launch(void* const* d_in, const int* in_sizes, int n_in,
                              void* d_out, int out_size, void* d_ws, size_t ws_size,
                              hipStream_t stream) {
    const float* x      = (const float*)d_in[0];
    const int*   ei     = (const int*)d_in[1];
    const int*   sub    = (const int*)d_in[2];
    const float* pre_w  = (const float*)d_in[3];
    const float* pre_b  = (const float*)d_in[4];
    const float* post_w = (const float*)d_in[5];
    const float* post_b = (const float*)d_in[6];
    const float* lin_w  = (const float*)d_in[7];
    const float* lin_b  = (const float*)d_in[8];
    const float* bn_g   = (const float*)d_in[9];
    const float* bn_b   = (const float*)d_in[10];
    const float* bn_m   = (const float*)d_in[11];
    const float* bn_v   = (const float*)d_in[12];
    const float* op_w   = (const float*)d_in[13];
    const float* op_b   = (const float*)d_in[14];
    float* out = (float*)d_out;

    char* p = (char*)d_ws;
    auto alloc = [&](size_t bytes) -> char* {
        char* q = p;
        p += (bytes + 255) & ~(size_t)255;
        return q;
    };

    char* zero_start = p;
    int* deg  = (int*)alloc(sizeof(int) * NN);
    int* ecur = (int*)alloc(sizeof(int) * NN);
    int* scnt = (int*)alloc(sizeof(int) * NS);
    int* scur = (int*)alloc(sizeof(int) * NS);
    size_t zero_span = (size_t)(p - zero_start);

    int* eoff   = (int*)alloc(sizeof(int) * (NN + 1));
    int* soff   = (int*)alloc(sizeof(int) * (NS + 1));
    int* csr    = (int*)alloc(sizeof(int) * NE);
    int* snodes = (int*)alloc(sizeof(int) * NN);
    float* h1     = (float*)alloc(sizeof(float) * (size_t)NN * D);
    float* h2     = (float*)alloc(sizeof(float) * (size_t)NN * D);
    float* h3     = (float*)alloc(sizeof(float) * (size_t)NN * D);
    float* sbuf   = (float*)alloc(sizeof(float) * (size_t)NN * D);
    float* pooled = (float*)alloc(sizeof(float) * (size_t)NS * INR);
    float* wefft  = (float*)alloc(sizeof(float) * (size_t)INR * D);
    float* beff   = (float*)alloc(sizeof(float) * D);
    float* cw     = (float*)alloc(sizeof(float) * NL * TW * 16 * 48);
    float* cv     = (float*)alloc(sizeof(float) * NL * TW * 16);

    hipMemsetAsync(zero_start, 0, zero_span, stream);

    count_kernel<<<(NE + 255) / 256, 256, 0, stream>>>(ei, sub, deg, scnt);
    scan2_kernel<<<2, 1024, 0, stream>>>(deg, eoff, scnt, soff);
    fill_kernel<<<(NE + 255) / 256, 256, 0, stream>>>(ei, sub, eoff, ecur, csr,
                                                      soff, scur, snodes);
    prep_kernel<<<312, 256, 0, stream>>>(pre_w, pre_b, post_w, cw, cv,
                                         op_w, op_b, bn_g, bn_b, bn_m, bn_v,
                                         wefft, beff);

    const float* hs[4] = { x, h1, h2, h3 };
    for (int l = 0; l < NL; ++l) {
        gather_kernel<<<(NN + 3) / 4, 256, 0, stream>>>(hs[l], eoff, csr, sbuf);
        update_kernel<<<640, 512, 0, stream>>>(hs[l], sbuf, deg, cw, cv,
                                               post_b, lin_w, lin_b,
                                               (float*)hs[l + 1], l);
    }

    pool_kernel<<<NS, 128, 0, stream>>>(x, h1, h2, h3, soff, snodes, pooled);
    out_kernel<<<NS / 16, 512, 0, stream>>>(pooled, wefft, beff, out);
}

// Round 6
// 348.727 us; speedup vs baseline: 1.7697x; 1.0181x over previous
//
#include <hip/hip_runtime.h>
#include <cstdint>
#include <cstddef>

#define NN 20000   // nodes
#define NE 320000  // edges
#define D  128     // embed dim
#define TW 8       // towers
#define FT 16      // per-tower features
#define NL 3       // layers
#define NS 4096    // subgraphs
#define INR 512    // (L+1)*D

// ---------------- CSR build ----------------

__global__ void count_kernel(const int* __restrict__ ei, const int* __restrict__ sub,
                             int* __restrict__ deg, int* __restrict__ scnt) {
    int i = blockIdx.x * blockDim.x + threadIdx.x;
    if (i < NE) atomicAdd(&deg[ei[NE + i]], 1);   // dst row
    if (i < NN) atomicAdd(&scnt[sub[i]], 1);
}

// two-block scan: block 0 -> (deg->eoff, NN), block 1 -> (scnt->soff, NS)
__global__ void scan2_kernel(const int* __restrict__ cnt0, int* __restrict__ off0,
                             const int* __restrict__ cnt1, int* __restrict__ off1) {
    __shared__ int lds[1024];
    const int tid = threadIdx.x;
    const int* cnt = blockIdx.x ? cnt1 : cnt0;
    int*       off = blockIdx.x ? off1 : off0;
    const int n   = blockIdx.x ? NS : NN;
    const int per = (n + 1023) >> 10;
    const int s = tid * per;
    const int e = min(s + per, n);
    int sum = 0;
    for (int i = s; i < e; ++i) sum += cnt[i];
    lds[tid] = sum;
    __syncthreads();
    for (int o = 1; o < 1024; o <<= 1) {
        int v = (tid >= o) ? lds[tid - o] : 0;
        __syncthreads();
        if (tid >= o) lds[tid] += v;
        __syncthreads();
    }
    int base = (tid == 0) ? 0 : lds[tid - 1];
    for (int i = s; i < e; ++i) { off[i] = base; base += cnt[i]; }
    if (tid == 1023) off[n] = lds[1023];
}

__global__ void fill_kernel(const int* __restrict__ ei, const int* __restrict__ sub,
                            const int* __restrict__ eoff, int* __restrict__ ecur,
                            int* __restrict__ csr,
                            const int* __restrict__ soff, int* __restrict__ scur,
                            int* __restrict__ snodes) {
    int i = blockIdx.x * blockDim.x + threadIdx.x;
    if (i < NE) {
        int dd = ei[NE + i];
        int p = atomicAdd(&ecur[dd], 1);
        csr[eoff[dd] + p] = ei[i];          // src
    }
    if (i < NN) {
        int g = sub[i];
        int p = atomicAdd(&scur[g], 1);
        snodes[soff[g] + p] = i;
    }
}

// ---------------- merged prep: towerprep (blk 0..23), weff (24..279), beff (280..311) ----
// towerprep: o = post_b + postA.x + (postB.B).s + deg*((postB.A).x + postB.pre_b)
// cw[lt][dd][0:16]=M1=postA row, [16:32]=M2=postB.A row, [32:48]=M3=postB.B row; cv=postB.pre_b
__global__ __launch_bounds__(256)
void prep_kernel(const float* __restrict__ pre_w, const float* __restrict__ pre_b,
                 const float* __restrict__ post_w,
                 float* __restrict__ cw, float* __restrict__ cv,
                 const float* __restrict__ op_w, const float* __restrict__ op_b,
                 const float* __restrict__ gma, const float* __restrict__ bta,
                 const float* __restrict__ mean, const float* __restrict__ var,
                 float* __restrict__ wefft, float* __restrict__ beff) {
    const int b = blockIdx.x;
    const int tid = threadIdx.x;
    if (b < 24) {                          // ---- tower fold
        const int lt = b;
        const int dd = tid >> 4;
        const int ff = tid & 15;
        const float* PW = pre_w  + (size_t)lt * (FT * 2 * FT);
        const float* QW = post_w + (size_t)lt * (FT * 2 * FT);
        const float* PB = pre_b  + (size_t)lt * FT;
        float m1 = QW[dd * 32 + ff];
        float m2 = 0.f, m3 = 0.f, v = 0.f;
        for (int k = 0; k < FT; ++k) {
            float pb = QW[dd * 32 + 16 + k];
            m2 = fmaf(pb, PW[k * 32 + ff], m2);
            m3 = fmaf(pb, PW[k * 32 + 16 + ff], m3);
            if (ff == 0) v = fmaf(pb, PB[k], v);
        }
        float* o = cw + ((size_t)lt * 16 + dd) * 48;
        o[ff] = m1; o[16 + ff] = m2; o[32 + ff] = m3;
        if (ff == 0) cv[lt * 16 + dd] = v;
    } else if (b < 280) {                  // ---- wefft[j][d] = op_w[d][j]*scale[j]
        int i = (b - 24) * 256 + tid;      // 65536 total
        int j = i >> 7, d = i & (D - 1);
        float sc = gma[j] * rsqrtf(var[j] + 1e-5f);
        wefft[(size_t)j * D + d] = op_w[(size_t)d * INR + j] * sc;
    } else {                               // ---- beff rows, 4 rows/block (one per wave)
        const int d = (b - 280) * 4 + (tid >> 6);
        const int lane = tid & 63;
        float acc = 0.f;
        for (int j = lane; j < INR; j += 64) {
            float sc = gma[j] * rsqrtf(var[j] + 1e-5f);
            float sh = bta[j] - mean[j] * sc;
            acc = fmaf(op_w[(size_t)d * INR + j], sh, acc);
        }
#pragma unroll
        for (int o = 32; o; o >>= 1) acc += __shfl_down(acc, o);
        if (lane == 0) beff[d] = acc + op_b[d];
    }
}

// ---------------- gather: sbuf[n,:] = sum_{src in in(n)} h[src,:] ----------------
// one wave per node; lanes 0-31 handle even edges, 32-63 odd (float4 over 128 dims)
__global__ __launch_bounds__(256)
void gather_kernel(const float* __restrict__ h, const int* __restrict__ eoff,
                   const int* __restrict__ csr, float* __restrict__ sbuf) {
    const int w    = threadIdx.x >> 6;
    const int lane = threadIdx.x & 63;
    const int node = blockIdx.x * 4 + w;
    if (node >= NN) return;
    const int e0 = eoff[node], e1 = eoff[node + 1];
    const int half = lane >> 5;
    const int q    = lane & 31;
    const float4* h4 = (const float4*)h;       // 32 float4 per node row
    float4 acc = make_float4(0.f, 0.f, 0.f, 0.f);
    int e = e0;
    for (; e + 8 <= e1; e += 8) {
#pragma unroll
        for (int k = 0; k < 4; ++k) {
            int s = csr[e + 2 * k + half];
            float4 v = h4[(size_t)s * 32 + q];
            acc.x += v.x; acc.y += v.y; acc.z += v.z; acc.w += v.w;
        }
    }
    for (; e < e1; e += 2) {
        int idx = e + half;
        bool valid = idx < e1;
        int s = csr[valid ? idx : e0];
        float4 v = h4[(size_t)s * 32 + q];
        if (valid) { acc.x += v.x; acc.y += v.y; acc.z += v.z; acc.w += v.w; }
    }
    acc.x += __shfl_xor(acc.x, 32);
    acc.y += __shfl_xor(acc.y, 32);
    acc.z += __shfl_xor(acc.z, 32);
    acc.w += __shfl_xor(acc.w, 32);
    if (half == 0) ((float4*)sbuf)[(size_t)node * 32 + q] = acc;
}

// ---------------- fused PNA update (v3: no XA/SB staging, 2 syncs/tile) ----------------
// NN = 1250*16 exactly -> no bounds guards needed.
__global__ __launch_bounds__(512, 4)
void update_kernel(const float* __restrict__ hin, const float* __restrict__ sbuf,
                   const int* __restrict__ deg,
                   const float* __restrict__ cw, const float* __restrict__ cv,
                   const float* __restrict__ post_b, const float* __restrict__ lin_w,
                   const float* __restrict__ lin_b, float* __restrict__ hout, int l) {
    __shared__ float LW[D * 132];     // 67584 B, padded rows (stride 132 -> conflict-free b128)
    __shared__ float OB[16 * D];      // 8192 B   -> total 75776 B (2 blocks/CU)

    const int tid = threadIdx.x;
    const int si  = tid >> 7;          // 0..3  (node sub-group)
    const int d   = tid & 127;
    const int t4  = (d & ~15) >> 2;    // float4 index of tower base within a 128-row
    const int dd  = d & 15;

    const float* wb = cw + ((size_t)(l * TW + (d >> 4)) * 16 + dd) * 48;
    float4 M1[4], M2[4], M3[4];
#pragma unroll
    for (int q = 0; q < 4; ++q) {
        M1[q] = ((const float4*)wb)[q];
        M2[q] = ((const float4*)(wb + 16))[q];
        M3[q] = ((const float4*)(wb + 32))[q];
    }
    const float vq = cv[(l * TW + (d >> 4)) * 16 + dd];
    const float cb = post_b[l * D + d];
    const float bl = lin_b[l * D + d];

    const float* lw = lin_w + (size_t)l * D * D;
    for (int i = tid; i < D * D; i += 512) LW[(i >> 7) * 132 + (i & 127)] = lw[i];
    // first __syncthreads below covers LW staging too

    const float4* hin4  = (const float4*)hin;
    const float4* sbuf4 = (const float4*)sbuf;

    const int ntiles = NN >> 4;        // 1250
    for (int tile = blockIdx.x; tile < ntiles; tile += gridDim.x) {
        const int n0 = tile << 4;
        // ---- compute this thread's 4 OB values in registers (overlaps prev matvec)
        float ovals[4];
#pragma unroll
        for (int u = 0; u < 4; ++u) {
            const int node = n0 + si * 4 + u;
            const float4* xa = hin4  + (size_t)node * 32 + t4;
            const float4* sb = sbuf4 + (size_t)node * 32 + t4;
            float ax = 0.f, am = 0.f, as = 0.f;
#pragma unroll
            for (int q = 0; q < 4; ++q) {
                float4 xq = xa[q], sq = sb[q];
                ax = fmaf(M1[q].x, xq.x, ax); ax = fmaf(M1[q].y, xq.y, ax);
                ax = fmaf(M1[q].z, xq.z, ax); ax = fmaf(M1[q].w, xq.w, ax);
                am = fmaf(M2[q].x, xq.x, am); am = fmaf(M2[q].y, xq.y, am);
                am = fmaf(M2[q].z, xq.z, am); am = fmaf(M2[q].w, xq.w, am);
                as = fmaf(M3[q].x, sq.x, as); as = fmaf(M3[q].y, sq.y, as);
                as = fmaf(M3[q].z, sq.z, as); as = fmaf(M3[q].w, sq.w, as);
            }
            const float dg = (float)deg[node];
            ovals[u] = cb + ax + as + dg * (am + vq);
        }
        __syncthreads();                 // prev tile's matvec done with OB (1st iter: LW staged)
#pragma unroll
        for (int u = 0; u < 4; ++u) OB[(si * 4 + u) * 128 + d] = ovals[u];
        __syncthreads();                 // OB ready
        // ---- matvec: group si handles nodes n0+si*4 .. +3, thread computes output row d
        float ac0 = 0.f, ac1 = 0.f, ac2 = 0.f, ac3 = 0.f;
        const float4* lrow = (const float4*)&LW[d * 132];
        const float4* ob   = (const float4*)&OB[si * 4 * 128];
#pragma unroll 8
        for (int k0 = 0; k0 < 32; ++k0) {
            float4 lv = lrow[k0];
            float4 o0 = ob[k0];
            float4 o1 = ob[32 + k0];
            float4 o2 = ob[64 + k0];
            float4 o3 = ob[96 + k0];
            ac0 = fmaf(lv.x, o0.x, ac0); ac0 = fmaf(lv.y, o0.y, ac0);
            ac0 = fmaf(lv.z, o0.z, ac0); ac0 = fmaf(lv.w, o0.w, ac0);
            ac1 = fmaf(lv.x, o1.x, ac1); ac1 = fmaf(lv.y, o1.y, ac1);
            ac1 = fmaf(lv.z, o1.z, ac1); ac1 = fmaf(lv.w, o1.w, ac1);
            ac2 = fmaf(lv.x, o2.x, ac2); ac2 = fmaf(lv.y, o2.y, ac2);
            ac2 = fmaf(lv.z, o2.z, ac2); ac2 = fmaf(lv.w, o2.w, ac2);
            ac3 = fmaf(lv.x, o3.x, ac3); ac3 = fmaf(lv.y, o3.y, ac3);
            ac3 = fmaf(lv.z, o3.z, ac3); ac3 = fmaf(lv.w, o3.w, ac3);
        }
        const int nb = n0 + si * 4;
        hout[(size_t)(nb + 0) * D + d] = fmaxf(ac0 + bl, 0.f);
        hout[(size_t)(nb + 1) * D + d] = fmaxf(ac1 + bl, 0.f);
        hout[(size_t)(nb + 2) * D + d] = fmaxf(ac2 + bl, 0.f);
        hout[(size_t)(nb + 3) * D + d] = fmaxf(ac3 + bl, 0.f);
    }
}

// ---------------- pooling + fused BN/out ----------------

__global__ __launch_bounds__(128)
void pool_kernel(const float* __restrict__ h0, const float* __restrict__ h1,
                 const float* __restrict__ h2, const float* __restrict__ h3,
                 const int* __restrict__ soff, const int* __restrict__ snodes,
                 float* __restrict__ pooled) {
    const int s = blockIdx.x;
    const int t = threadIdx.x;
    const int seg = t >> 5, q = t & 31;
    const float* hs = (seg == 0) ? h0 : (seg == 1) ? h1 : (seg == 2) ? h2 : h3;
    const int a0 = soff[s], a1 = soff[s + 1];
    float4 acc = make_float4(0.f, 0.f, 0.f, 0.f);
    for (int a = a0; a < a1; ++a) {
        int n = snodes[a];
        float4 v = ((const float4*)hs)[(size_t)n * 32 + q];
        acc.x += v.x; acc.y += v.y; acc.z += v.z; acc.w += v.w;
    }
    ((float4*)pooled)[(size_t)s * 128 + seg * 32 + q] = acc;
}

// 16 subgraphs/block, 512 threads = 4 j-quarters x 128 d
__global__ __launch_bounds__(512)
void out_kernel(const float* __restrict__ pooled, const float* __restrict__ wefft,
                const float* __restrict__ beff, float* __restrict__ out) {
    __shared__ float sm[16 * INR];   // 32 KB; phase2 reuses as partial[4][16][128]
    const int tid = threadIdx.x;
    const int q = tid >> 7;
    const int d = tid & 127;
    const int s0 = blockIdx.x * 16;
    {
        const float4* src = (const float4*)(pooled + (size_t)s0 * INR);
        float4* dst = (float4*)sm;
        for (int i = tid; i < 16 * INR / 4; i += 512) dst[i] = src[i];
    }
    __syncthreads();
    float acc[16];
#pragma unroll
    for (int i = 0; i < 16; ++i) acc[i] = 0.f;
    // 4 jj per iteration: 4 independent global loads + 16 ds_read_b128 broadcasts + 64 FMA
    for (int jj4 = 0; jj4 < 32; ++jj4) {
        const int j0 = q * 128 + jj4 * 4;
        float wv0 = wefft[(size_t)(j0 + 0) * D + d];
        float wv1 = wefft[(size_t)(j0 + 1) * D + d];
        float wv2 = wefft[(size_t)(j0 + 2) * D + d];
        float wv3 = wefft[(size_t)(j0 + 3) * D + d];
#pragma unroll
        for (int i = 0; i < 16; ++i) {
            float4 pv = *(const float4*)&sm[i * INR + j0];
            acc[i] = fmaf(pv.x, wv0, acc[i]);
            acc[i] = fmaf(pv.y, wv1, acc[i]);
            acc[i] = fmaf(pv.z, wv2, acc[i]);
            acc[i] = fmaf(pv.w, wv3, acc[i]);
        }
    }
    __syncthreads();
#pragma unroll
    for (int i = 0; i < 16; ++i) sm[(q * 16 + i) * 128 + d] = acc[i];
    __syncthreads();
    const float bb = beff[d];
#pragma unroll
    for (int ii = 0; ii < 4; ++ii) {
        int i = q * 4 + ii;
        float v = sm[i * 128 + d] + sm[(16 + i) * 128 + d]
                + sm[(32 + i) * 128 + d] + sm[(48 + i) * 128 + d];
        out[(size_t)(s0 + i) * D + d] = v + bb;
    }
}

// ---------------- launch ----------------

extern "C" void kernel_launch(void* const* d_in, const int* in_sizes, int n_in,
                              void* d_out, int out_size, void* d_ws, size_t ws_size,
                              hipStream_t stream) {
    const float* x      = (const float*)d_in[0];
    const int*   ei     = (const int*)d_in[1];
    const int*   sub    = (const int*)d_in[2];
    const float* pre_w  = (const float*)d_in[3];
    const float* pre_b  = (const float*)d_in[4];
    const float* post_w = (const float*)d_in[5];
    const float* post_b = (const float*)d_in[6];
    const float* lin_w  = (const float*)d_in[7];
    const float* lin_b  = (const float*)d_in[8];
    const float* bn_g   = (const float*)d_in[9];
    const float* bn_b   = (const float*)d_in[10];
    const float* bn_m   = (const float*)d_in[11];
    const float* bn_v   = (const float*)d_in[12];
    const float* op_w   = (const float*)d_in[13];
    const float* op_b   = (const float*)d_in[14];
    float* out = (float*)d_out;

    char* p = (char*)d_ws;
    auto alloc = [&](size_t bytes) -> char* {
        char* q = p;
        p += (bytes + 255) & ~(size_t)255;
        return q;
    };

    char* zero_start = p;
    int* deg  = (int*)alloc(sizeof(int) * NN);
    int* ecur = (int*)alloc(sizeof(int) * NN);
    int* scnt = (int*)alloc(sizeof(int) * NS);
    int* scur = (int*)alloc(sizeof(int) * NS);
    size_t zero_span = (size_t)(p - zero_start);

    int* eoff   = (int*)alloc(sizeof(int) * (NN + 1));
    int* soff   = (int*)alloc(sizeof(int) * (NS + 1));
    int* csr    = (int*)alloc(sizeof(int) * NE);
    int* snodes = (int*)alloc(sizeof(int) * NN);
    float* h1     = (float*)alloc(sizeof(float) * (size_t)NN * D);
    float* h2     = (float*)alloc(sizeof(float) * (size_t)NN * D);
    float* h3     = (float*)alloc(sizeof(float) * (size_t)NN * D);
    float* sbuf   = (float*)alloc(sizeof(float) * (size_t)NN * D);
    float* pooled = (float*)alloc(sizeof(float) * (size_t)NS * INR);
    float* wefft  = (float*)alloc(sizeof(float) * (size_t)INR * D);
    float* beff   = (float*)alloc(sizeof(float) * D);
    float* cw     = (float*)alloc(sizeof(float) * NL * TW * 16 * 48);
    float* cv     = (float*)alloc(sizeof(float) * NL * TW * 16);

    hipMemsetAsync(zero_start, 0, zero_span, stream);

    count_kernel<<<(NE + 255) / 256, 256, 0, stream>>>(ei, sub, deg, scnt);
    scan2_kernel<<<2, 1024, 0, stream>>>(deg, eoff, scnt, soff);
    fill_kernel<<<(NE + 255) / 256, 256, 0, stream>>>(ei, sub, eoff, ecur, csr,
                                                      soff, scur, snodes);
    prep_kernel<<<312, 256, 0, stream>>>(pre_w, pre_b, post_w, cw, cv,
                                         op_w, op_b, bn_g, bn_b, bn_m, bn_v,
                                         wefft, beff);

    const float* hs[4] = { x, h1, h2, h3 };
    for (int l = 0; l < NL; ++l) {
        gather_kernel<<<(NN + 3) / 4, 256, 0, stream>>>(hs[l], eoff, csr, sbuf);
        update_kernel<<<640, 512, 0, stream>>>(hs[l], sbuf, deg, cw, cv,
                                               post_b, lin_w, lin_b,
                                               (float*)hs[l + 1], l);
    }

    pool_kernel<<<NS, 128, 0, stream>>>(x, h1, h2, h3, soff, snodes, pooled);
    out_kernel<<<NS / 16, 512, 0, stream>>>(pooled, wefft, beff, out);
}

// Round 7
// 283.118 us; speedup vs baseline: 2.1799x; 1.2317x over previous
//
#include <hip/hip_runtime.h>
#include <cstdint>
#include <cstddef>

#define NN 20000   // nodes
#define NE 320000  // edges
#define D  128     // embed dim
#define TW 8       // towers
#define FT 16      // per-tower features
#define NL 3       // layers
#define NS 4096    // subgraphs
#define INR 512    // (L+1)*D

typedef unsigned short u16;
typedef __attribute__((ext_vector_type(8))) short short8;
typedef __attribute__((ext_vector_type(4))) float f32x4;

__device__ __forceinline__ float b2f(short s) {
    return __uint_as_float(((unsigned)(u16)s) << 16);
}
__device__ __forceinline__ u16 f2b(float f) {
    unsigned u = __float_as_uint(f);
    return (u16)((u + 0x7FFF + ((u >> 16) & 1)) >> 16);   // RNE
}

// ---------------- CSR build ----------------

__global__ void count_kernel(const int* __restrict__ ei, const int* __restrict__ sub,
                             int* __restrict__ deg, int* __restrict__ scnt) {
    int i = blockIdx.x * blockDim.x + threadIdx.x;
    if (i < NE) atomicAdd(&deg[ei[NE + i]], 1);   // dst row
    if (i < NN) atomicAdd(&scnt[sub[i]], 1);
}

__global__ void scan2_kernel(const int* __restrict__ cnt0, int* __restrict__ off0,
                             const int* __restrict__ cnt1, int* __restrict__ off1) {
    __shared__ int lds[1024];
    const int tid = threadIdx.x;
    const int* cnt = blockIdx.x ? cnt1 : cnt0;
    int*       off = blockIdx.x ? off1 : off0;
    const int n   = blockIdx.x ? NS : NN;
    const int per = (n + 1023) >> 10;
    const int s = tid * per;
    const int e = min(s + per, n);
    int sum = 0;
    for (int i = s; i < e; ++i) sum += cnt[i];
    lds[tid] = sum;
    __syncthreads();
    for (int o = 1; o < 1024; o <<= 1) {
        int v = (tid >= o) ? lds[tid - o] : 0;
        __syncthreads();
        if (tid >= o) lds[tid] += v;
        __syncthreads();
    }
    int base = (tid == 0) ? 0 : lds[tid - 1];
    for (int i = s; i < e; ++i) { off[i] = base; base += cnt[i]; }
    if (tid == 1023) off[n] = lds[1023];
}

__global__ void fill_kernel(const int* __restrict__ ei, const int* __restrict__ sub,
                            const int* __restrict__ eoff, int* __restrict__ ecur,
                            int* __restrict__ csr,
                            const int* __restrict__ soff, int* __restrict__ scur,
                            int* __restrict__ snodes) {
    int i = blockIdx.x * blockDim.x + threadIdx.x;
    if (i < NE) {
        int dd = ei[NE + i];
        int p = atomicAdd(&ecur[dd], 1);
        csr[eoff[dd] + p] = ei[i];          // src
    }
    if (i < NN) {
        int g = sub[i];
        int p = atomicAdd(&scur[g], 1);
        snodes[soff[g] + p] = i;
    }
}

// ---------------- merged prep ----------------
// blocks: 0..23 tower-fold | 24..279 weff | 280..311 beff | 312..335 lin B-frag pack
//         | 336..1585 x->bf16 copy
__global__ __launch_bounds__(256)
void prep_kernel(const float* __restrict__ pre_w, const float* __restrict__ pre_b,
                 const float* __restrict__ post_w,
                 float* __restrict__ cw, float* __restrict__ cv,
                 const float* __restrict__ op_w, const float* __restrict__ op_b,
                 const float* __restrict__ gma, const float* __restrict__ bta,
                 const float* __restrict__ mean, const float* __restrict__ var,
                 float* __restrict__ wefft, float* __restrict__ beff,
                 const float* __restrict__ lin_w, u16* __restrict__ packB,
                 const float* __restrict__ x, u16* __restrict__ xbf) {
    const int b = blockIdx.x;
    const int tid = threadIdx.x;
    if (b < 24) {                          // ---- tower fold (fp32)
        const int lt = b;
        const int dd = tid >> 4;
        const int ff = tid & 15;
        const float* PW = pre_w  + (size_t)lt * (FT * 2 * FT);
        const float* QW = post_w + (size_t)lt * (FT * 2 * FT);
        const float* PB = pre_b  + (size_t)lt * FT;
        float m1 = QW[dd * 32 + ff];
        float m2 = 0.f, m3 = 0.f, v = 0.f;
        for (int k = 0; k < FT; ++k) {
            float pb = QW[dd * 32 + 16 + k];
            m2 = fmaf(pb, PW[k * 32 + ff], m2);
            m3 = fmaf(pb, PW[k * 32 + 16 + ff], m3);
            if (ff == 0) v = fmaf(pb, PB[k], v);
        }
        float* o = cw + ((size_t)lt * 16 + dd) * 48;
        o[ff] = m1; o[16 + ff] = m2; o[32 + ff] = m3;
        if (ff == 0) cv[lt * 16 + dd] = v;
    } else if (b < 280) {                  // ---- wefft[j][d] = op_w[d][j]*scale[j]
        int i = (b - 24) * 256 + tid;
        int j = i >> 7, d = i & (D - 1);
        float sc = gma[j] * rsqrtf(var[j] + 1e-5f);
        wefft[(size_t)j * D + d] = op_w[(size_t)d * INR + j] * sc;
    } else if (b < 312) {                  // ---- beff rows (4/block)
        const int d = (b - 280) * 4 + (tid >> 6);
        const int lane = tid & 63;
        float acc = 0.f;
        for (int j = lane; j < INR; j += 64) {
            float sc = gma[j] * rsqrtf(var[j] + 1e-5f);
            float sh = bta[j] - mean[j] * sc;
            acc = fmaf(op_w[(size_t)d * INR + j], sh, acc);
        }
#pragma unroll
        for (int o = 32; o; o >>= 1) acc += __shfl_down(acc, o);
        if (lane == 0) beff[d] = acc + op_b[d];
    } else if (b < 336) {                  // ---- pack lin_w into per-lane MFMA B-frags
        const int lt = b - 312;            // l*8 + ct
        const int l  = lt >> 3, ct = lt & 7;
        const int ks = tid >> 6;           // 0..3
        const int lane = tid & 63;
        const int col = ct * 16 + (lane & 15);
        const int k0  = ks * 32 + ((lane >> 4) & 3) * 8;
        const float* lw = lin_w + (size_t)l * D * D + (size_t)col * D + k0;
        u16* o = packB + ((size_t)(lt * 4 + ks) * 64 + lane) * 8;
#pragma unroll
        for (int j = 0; j < 8; ++j) o[j] = f2b(lw[j]);
    } else {                               // ---- x -> bf16 copy (2048 elems/block)
        const size_t base = (size_t)(b - 336) * 2048 + (size_t)tid * 8;
        float4 a = *(const float4*)(x + base);
        float4 c = *(const float4*)(x + base + 4);
        u16 o[8] = { f2b(a.x), f2b(a.y), f2b(a.z), f2b(a.w),
                     f2b(c.x), f2b(c.y), f2b(c.z), f2b(c.w) };
        uint4 u;
        u.x = (unsigned)o[0] | ((unsigned)o[1] << 16);
        u.y = (unsigned)o[2] | ((unsigned)o[3] << 16);
        u.z = (unsigned)o[4] | ((unsigned)o[5] << 16);
        u.w = (unsigned)o[6] | ((unsigned)o[7] << 16);
        *(uint4*)(xbf + base) = u;
    }
}

// ---------------- gather (bf16 in, fp32 out) ----------------
// one wave/node; lanes 0-31 even edges, 32-63 odd; lane q handles dims 4q..4q+3
__global__ __launch_bounds__(256)
void gather_kernel(const u16* __restrict__ h, const int* __restrict__ eoff,
                   const int* __restrict__ csr, float* __restrict__ sbuf) {
    const int w    = threadIdx.x >> 6;
    const int lane = threadIdx.x & 63;
    const int node = blockIdx.x * 4 + w;
    if (node >= NN) return;
    const int e0 = eoff[node], e1 = eoff[node + 1];
    const int half = lane >> 5;
    const int q    = lane & 31;
    const uint2* h2 = (const uint2*)h;         // 8 B = 4 bf16; 32 per row
    float ax = 0.f, ay = 0.f, az = 0.f, aw = 0.f;
    int e = e0;
    for (; e + 8 <= e1; e += 8) {
#pragma unroll
        for (int k = 0; k < 4; ++k) {
            int s = csr[e + 2 * k + half];
            uint2 v = h2[(size_t)s * 32 + q];
            ax += __uint_as_float(v.x << 16);
            ay += __uint_as_float(v.x & 0xFFFF0000u);
            az += __uint_as_float(v.y << 16);
            aw += __uint_as_float(v.y & 0xFFFF0000u);
        }
    }
    for (; e < e1; e += 2) {
        int idx = e + half;
        bool valid = idx < e1;
        int s = valid ? csr[idx] : 0;
        uint2 v = h2[(size_t)s * 32 + q];
        if (valid) {
            ax += __uint_as_float(v.x << 16);
            ay += __uint_as_float(v.x & 0xFFFF0000u);
            az += __uint_as_float(v.y << 16);
            aw += __uint_as_float(v.y & 0xFFFF0000u);
        }
    }
    ax += __shfl_xor(ax, 32);
    ay += __shfl_xor(ay, 32);
    az += __shfl_xor(az, 32);
    aw += __shfl_xor(aw, 32);
    if (half == 0) {
        float4 r; r.x = ax; r.y = ay; r.z = az; r.w = aw;
        ((float4*)sbuf)[(size_t)node * 32 + q] = r;
    }
}

// ---------------- fused PNA update v4: fp32 tower + bf16 MFMA matvec ----------------
// 16 nodes/block. OUT[16x128] = OB[16x128] @ lin^T via 8 waves x (16x16x32 MFMA, 4 K-steps)
__global__ __launch_bounds__(512, 4)
void update_kernel(const u16* __restrict__ hin, const float* __restrict__ sbuf,
                   const int* __restrict__ deg,
                   const float* __restrict__ cw, const float* __restrict__ cv,
                   const float* __restrict__ post_b, const u16* __restrict__ packB,
                   const float* __restrict__ lin_b, u16* __restrict__ hout, int l) {
    __shared__ u16 OBS[16 * 136];      // 16 rows x 128 bf16, padded stride 136 (4352 B)

    const int tid  = threadIdx.x;
    const int si   = tid >> 7;         // 0..3 node sub-group (tower phase)
    const int d    = tid & 127;
    const int t16  = d & ~15;
    const int dd   = d & 15;
    const int lane = tid & 63;
    const int ct   = tid >> 6;         // wave id = output column tile (MFMA phase)

    // tower weights: row d needs 48 floats
    const float* wb = cw + ((size_t)(l * TW + (d >> 4)) * 16 + dd) * 48;
    const float4* wb4 = (const float4*)wb;
    float m1[16], m2[16], m3[16];
#pragma unroll
    for (int qq = 0; qq < 4; ++qq) {
        float4 t1 = wb4[qq], t2 = wb4[4 + qq], t3 = wb4[8 + qq];
        m1[qq*4+0]=t1.x; m1[qq*4+1]=t1.y; m1[qq*4+2]=t1.z; m1[qq*4+3]=t1.w;
        m2[qq*4+0]=t2.x; m2[qq*4+1]=t2.y; m2[qq*4+2]=t2.z; m2[qq*4+3]=t2.w;
        m3[qq*4+0]=t3.x; m3[qq*4+1]=t3.y; m3[qq*4+2]=t3.z; m3[qq*4+3]=t3.w;
    }
    const float vq = cv[(l * TW + (d >> 4)) * 16 + dd];
    const float cb = post_b[l * D + d];

    // MFMA B-fragments for this wave's column tile (packed by prep)
    short8 BF[4];
    {
        const short8* pB = (const short8*)packB + (size_t)((l * 8 + ct) * 4) * 64 + lane;
#pragma unroll
        for (int ks = 0; ks < 4; ++ks) BF[ks] = pB[ks * 64];
    }
    const float bl = lin_b[l * D + ct * 16 + (lane & 15)];

    const int n0 = blockIdx.x << 4;

    // ---- tower (fp32): this thread's 4 OB values
    float ovals[4];
    const float4* sbuf4 = (const float4*)sbuf;
#pragma unroll
    for (int u = 0; u < 4; ++u) {
        const int node = n0 + si * 4 + u;
        const short8* hp = (const short8*)(hin + (size_t)node * D + t16);
        short8 hx0 = hp[0], hx1 = hp[1];
        const float4* sp = sbuf4 + (size_t)node * 32 + (t16 >> 2);
        float4 sv0 = sp[0], sv1 = sp[1], sv2 = sp[2], sv3 = sp[3];
        float ax = 0.f, am = 0.f, as2 = 0.f;
#pragma unroll
        for (int j = 0; j < 8; ++j) {
            float xf = b2f(hx0[j]);
            ax = fmaf(m1[j], xf, ax);
            am = fmaf(m2[j], xf, am);
        }
#pragma unroll
        for (int j = 0; j < 8; ++j) {
            float xf = b2f(hx1[j]);
            ax = fmaf(m1[8 + j], xf, ax);
            am = fmaf(m2[8 + j], xf, am);
        }
        as2 = fmaf(m3[0], sv0.x, as2); as2 = fmaf(m3[1], sv0.y, as2);
        as2 = fmaf(m3[2], sv0.z, as2); as2 = fmaf(m3[3], sv0.w, as2);
        as2 = fmaf(m3[4], sv1.x, as2); as2 = fmaf(m3[5], sv1.y, as2);
        as2 = fmaf(m3[6], sv1.z, as2); as2 = fmaf(m3[7], sv1.w, as2);
        as2 = fmaf(m3[8], sv2.x, as2); as2 = fmaf(m3[9], sv2.y, as2);
        as2 = fmaf(m3[10], sv2.z, as2); as2 = fmaf(m3[11], sv2.w, as2);
        as2 = fmaf(m3[12], sv3.x, as2); as2 = fmaf(m3[13], sv3.y, as2);
        as2 = fmaf(m3[14], sv3.z, as2); as2 = fmaf(m3[15], sv3.w, as2);
        const float dg = (float)deg[node];
        ovals[u] = cb + ax + as2 + dg * (am + vq);
    }
#pragma unroll
    for (int u = 0; u < 4; ++u) OBS[(si * 4 + u) * 136 + d] = f2b(ovals[u]);
    __syncthreads();

    // ---- MFMA matvec: wave ct computes OUT[0:16][ct*16 : +16]
    f32x4 c = {0.f, 0.f, 0.f, 0.f};
#pragma unroll
    for (int ks = 0; ks < 4; ++ks) {
        const short8 a = *(const short8*)((const char*)OBS +
                            (lane & 15) * 272 + (ks * 4 + (lane >> 4)) * 16);
        c = __builtin_amdgcn_mfma_f32_16x16x32_bf16(a, BF[ks], c, 0, 0, 0);
    }
    const int d_epi = ct * 16 + (lane & 15);
#pragma unroll
    for (int r = 0; r < 4; ++r) {
        const int node = n0 + (lane >> 4) * 4 + r;   // C: col=lane&15, row=(lane>>4)*4+r
        float v = fmaxf(c[r] + bl, 0.f);
        hout[(size_t)node * D + d_epi] = f2b(v);
    }
}

// ---------------- pooling (bf16 in, fp32 out) ----------------

__global__ __launch_bounds__(128)
void pool_kernel(const u16* __restrict__ h0, const u16* __restrict__ h1,
                 const u16* __restrict__ h2, const u16* __restrict__ h3,
                 const int* __restrict__ soff, const int* __restrict__ snodes,
                 float* __restrict__ pooled) {
    const int s = blockIdx.x;
    const int t = threadIdx.x;
    const int seg = t >> 5, q = t & 31;
    const u16* hs = (seg == 0) ? h0 : (seg == 1) ? h1 : (seg == 2) ? h2 : h3;
    const uint2* hv = (const uint2*)hs;
    const int a0 = soff[s], a1 = soff[s + 1];
    float ax = 0.f, ay = 0.f, az = 0.f, aw = 0.f;
    for (int a = a0; a < a1; ++a) {
        int n = snodes[a];
        uint2 v = hv[(size_t)n * 32 + q];
        ax += __uint_as_float(v.x << 16);
        ay += __uint_as_float(v.x & 0xFFFF0000u);
        az += __uint_as_float(v.y << 16);
        aw += __uint_as_float(v.y & 0xFFFF0000u);
    }
    float4 r; r.x = ax; r.y = ay; r.z = az; r.w = aw;
    ((float4*)pooled)[(size_t)s * 128 + seg * 32 + q] = r;
}

// ---------------- fused BN + out GEMM ----------------

__global__ __launch_bounds__(512)
void out_kernel(const float* __restrict__ pooled, const float* __restrict__ wefft,
                const float* __restrict__ beff, float* __restrict__ out) {
    __shared__ float sm[16 * INR];   // 32 KB; phase2 reuses as partial[4][16][128]
    const int tid = threadIdx.x;
    const int q = tid >> 7;
    const int d = tid & 127;
    const int s0 = blockIdx.x * 16;
    {
        const float4* src = (const float4*)(pooled + (size_t)s0 * INR);
        float4* dst = (float4*)sm;
        for (int i = tid; i < 16 * INR / 4; i += 512) dst[i] = src[i];
    }
    __syncthreads();
    float acc[16];
#pragma unroll
    for (int i = 0; i < 16; ++i) acc[i] = 0.f;
    for (int jj4 = 0; jj4 < 32; ++jj4) {
        const int j0 = q * 128 + jj4 * 4;
        float wv0 = wefft[(size_t)(j0 + 0) * D + d];
        float wv1 = wefft[(size_t)(j0 + 1) * D + d];
        float wv2 = wefft[(size_t)(j0 + 2) * D + d];
        float wv3 = wefft[(size_t)(j0 + 3) * D + d];
#pragma unroll
        for (int i = 0; i < 16; ++i) {
            float4 pv = *(const float4*)&sm[i * INR + j0];
            acc[i] = fmaf(pv.x, wv0, acc[i]);
            acc[i] = fmaf(pv.y, wv1, acc[i]);
            acc[i] = fmaf(pv.z, wv2, acc[i]);
            acc[i] = fmaf(pv.w, wv3, acc[i]);
        }
    }
    __syncthreads();
#pragma unroll
    for (int i = 0; i < 16; ++i) sm[(q * 16 + i) * 128 + d] = acc[i];
    __syncthreads();
    const float bb = beff[d];
#pragma unroll
    for (int ii = 0; ii < 4; ++ii) {
        int i = q * 4 + ii;
        float v = sm[i * 128 + d] + sm[(16 + i) * 128 + d]
                + sm[(32 + i) * 128 + d] + sm[(48 + i) * 128 + d];
        out[(size_t)(s0 + i) * D + d] = v + bb;
    }
}

// ---------------- launch ----------------

extern "C" void kernel_launch(void* const* d_in, const int* in_sizes, int n_in,
                              void* d_out, int out_size, void* d_ws, size_t ws_size,
                              hipStream_t stream) {
    const float* x      = (const float*)d_in[0];
    const int*   ei     = (const int*)d_in[1];
    const int*   sub    = (const int*)d_in[2];
    const float* pre_w  = (const float*)d_in[3];
    const float* pre_b  = (const float*)d_in[4];
    const float* post_w = (const float*)d_in[5];
    const float* post_b = (const float*)d_in[6];
    const float* lin_w  = (const float*)d_in[7];
    const float* lin_b  = (const float*)d_in[8];
    const float* bn_g   = (const float*)d_in[9];
    const float* bn_b   = (const float*)d_in[10];
    const float* bn_m   = (const float*)d_in[11];
    const float* bn_v   = (const float*)d_in[12];
    const float* op_w   = (const float*)d_in[13];
    const float* op_b   = (const float*)d_in[14];
    float* out = (float*)d_out;

    char* p = (char*)d_ws;
    auto alloc = [&](size_t bytes) -> char* {
        char* q = p;
        p += (bytes + 255) & ~(size_t)255;
        return q;
    };

    char* zero_start = p;
    int* deg  = (int*)alloc(sizeof(int) * NN);
    int* ecur = (int*)alloc(sizeof(int) * NN);
    int* scnt = (int*)alloc(sizeof(int) * NS);
    int* scur = (int*)alloc(sizeof(int) * NS);
    size_t zero_span = (size_t)(p - zero_start);

    int* eoff   = (int*)alloc(sizeof(int) * (NN + 1));
    int* soff   = (int*)alloc(sizeof(int) * (NS + 1));
    int* csr    = (int*)alloc(sizeof(int) * NE);
    int* snodes = (int*)alloc(sizeof(int) * NN);
    u16* xbf    = (u16*)alloc(sizeof(u16) * (size_t)NN * D);
    u16* h1     = (u16*)alloc(sizeof(u16) * (size_t)NN * D);
    u16* h2     = (u16*)alloc(sizeof(u16) * (size_t)NN * D);
    u16* h3     = (u16*)alloc(sizeof(u16) * (size_t)NN * D);
    float* sbuf   = (float*)alloc(sizeof(float) * (size_t)NN * D);
    float* pooled = (float*)alloc(sizeof(float) * (size_t)NS * INR);
    float* wefft  = (float*)alloc(sizeof(float) * (size_t)INR * D);
    float* beff   = (float*)alloc(sizeof(float) * D);
    float* cw     = (float*)alloc(sizeof(float) * NL * TW * 16 * 48);
    float* cv     = (float*)alloc(sizeof(float) * NL * TW * 16);
    u16* packB    = (u16*)alloc(sizeof(u16) * NL * 8 * 4 * 64 * 8);

    hipMemsetAsync(zero_start, 0, zero_span, stream);

    count_kernel<<<(NE + 255) / 256, 256, 0, stream>>>(ei, sub, deg, scnt);
    scan2_kernel<<<2, 1024, 0, stream>>>(deg, eoff, scnt, soff);
    fill_kernel<<<(NE + 255) / 256, 256, 0, stream>>>(ei, sub, eoff, ecur, csr,
                                                      soff, scur, snodes);
    prep_kernel<<<1586, 256, 0, stream>>>(pre_w, pre_b, post_w, cw, cv,
                                          op_w, op_b, bn_g, bn_b, bn_m, bn_v,
                                          wefft, beff, lin_w, packB, x, xbf);

    const u16* hs[4] = { xbf, h1, h2, h3 };
    for (int l = 0; l < NL; ++l) {
        gather_kernel<<<(NN + 3) / 4, 256, 0, stream>>>(hs[l], eoff, csr, sbuf);
        update_kernel<<<NN / 16, 512, 0, stream>>>(hs[l], sbuf, deg, cw, cv,
                                                   post_b, packB, lin_b,
                                                   (u16*)hs[l + 1], l);
    }

    pool_kernel<<<NS, 128, 0, stream>>>(xbf, h1, h2, h3, soff, snodes, pooled);
    out_kernel<<<NS / 16, 512, 0, stream>>>(pooled, wefft, beff, out);
}